// Round 3
// baseline (220.068 us; speedup 1.0000x reference)
//
#include <hip/hip_runtime.h>

typedef __bf16 bf16x8 __attribute__((ext_vector_type(8)));
typedef float f32x4 __attribute__((ext_vector_type(4)));

__device__ __forceinline__ unsigned short f2bf(float f) {
    unsigned int u = __builtin_bit_cast(unsigned int, f);
    u += 0x7fffu + ((u >> 16) & 1u);
    return (unsigned short)(u >> 16);
}
__device__ __forceinline__ float bf2f(unsigned short u) {
    return __builtin_bit_cast(float, (unsigned)u << 16);
}

// XOR swizzle for 1024B-row LDS tiles: byte ^= ((row&7)<<4)
__device__ __forceinline__ unsigned swz1k(unsigned byte) {
    return byte ^ ((byte >> 6) & 0x70u);
}

// ---------------- K1: Pc[kc][j][t] = M[kc*32+t][j], M = Wq^T Wk  (bf16)
// plus Wv -> bf16 copy.
__global__ __launch_bounds__(256) void prep_kernel(
    const float* __restrict__ Wq, const float* __restrict__ Wk,
    const float* __restrict__ Wv, unsigned short* __restrict__ Pc,
    unsigned short* __restrict__ Wvb)
{
    int b = blockIdx.x;
    if (b < 1024) {
        int j0 = (b >> 4) * 8;
        int kc = b & 15;
        int jloc = threadIdx.x >> 5;
        int t = threadIdx.x & 31;
        int j = j0 + jloc, d = kc * 32 + t;
        float acc = 0.f;
        #pragma unroll 8
        for (int e = 0; e < 512; ++e)
            acc = fmaf(Wk[e * 512 + j], Wq[e * 512 + d], acc);
        Pc[((kc * 512) + j) * 32 + t] = f2bf(acc);
    } else {
        int i = (b - 1024) * 256 + (int)threadIdx.x;
        Wvb[i] = f2bf(Wv[i]);
    }
}

// ---------------- K2: fused main kernel. 1 block = 2 batches = 32 H rows.
// LDS 64.1 KB -> 2 blocks/CU (16 waves/CU).
// Phase 1: H f32 -> bf16 LDS (swizzled)           [barrier]
// Phase 2: T = Hbf @ M  (B-frags direct from global/L2, reg dbuf, no barriers)
//          T -> bf16 LDS                           [barrier]
// Phase 3: waves 0-1: scores+softmax+w ; waves 2-5: residual F-pool -> out
//                                                  [barrier]
// Phase 4: all 8 waves: g = sum_k w[k] H[k,:] (bf16 from LDS) -> ws
__global__ __launch_bounds__(512, 4) void attn_main_kernel(
    const float* __restrict__ H, const float* __restrict__ F,
    const unsigned short* __restrict__ Pc,
    float* __restrict__ out, unsigned short* __restrict__ g_ws)
{
    extern __shared__ char smem[];
    char* HBF = smem;                        // 32 rows x 1024B, swizzled (32 KB)
    char* TBF = smem + 32768;                // 32 rows x 1024B, swizzled (32 KB)
    float* wbuf = (float*)(smem + 65536);    // [2][16]

    const int tid = threadIdx.x;
    const int wv = tid >> 6;
    const int ln = tid & 63;
    const int rl = ln & 15;   // fragment row/col within tile
    const int kg = ln >> 4;   // k-group 0..3
    const long long gr0 = (long long)blockIdx.x * 32;

    // ---- Phase 1: stage H (fp32 global, coalesced) -> bf16 swizzled LDS
    {
        const float4* src = (const float4*)(H + gr0 * 512);
        #pragma unroll
        for (int rep = 0; rep < 8; ++rep) {
            int idx = rep * 512 + tid;                 // float4 index in [0,4096)
            float4 v = src[idx];
            ushort4 bv;
            bv.x = f2bf(v.x); bv.y = f2bf(v.y); bv.z = f2bf(v.z); bv.w = f2bf(v.w);
            unsigned byte = (unsigned)(idx >> 7) * 1024u + (unsigned)(idx & 127) * 8u;
            *(ushort4*)(HBF + swz1k(byte)) = bv;
        }
    }

    // B-fragment base (elements): Pc[((kc*512 + j)*32 + kg*8)], j = wv*64+jj*16+rl
    const unsigned short* bptr = Pc + ((wv * 64 + rl) * 32 + kg * 8);

    f32x4 acc[2][4];
    #pragma unroll
    for (int i = 0; i < 2; ++i)
        #pragma unroll
        for (int jj = 0; jj < 4; ++jj)
            acc[i][jj] = f32x4{0.f, 0.f, 0.f, 0.f};

    bf16x8 bcur[4];
    #pragma unroll
    for (int jj = 0; jj < 4; ++jj)
        bcur[jj] = *(const bf16x8*)(bptr + jj * 512);

    __syncthreads();   // HBF ready

    // ---- Phase 2: streaming GEMM, zero barriers
    #pragma unroll 2
    for (int kc = 0; kc < 16; ++kc) {
        bf16x8 bnext[4];
        if (kc < 15) {
            #pragma unroll
            for (int jj = 0; jj < 4; ++jj)
                bnext[jj] = *(const bf16x8*)(bptr + (kc + 1) * 16384 + jj * 512);
        }
        bf16x8 a[2];
        #pragma unroll
        for (int i = 0; i < 2; ++i) {
            unsigned off = (unsigned)(i * 16 + rl) * 1024u + (unsigned)kc * 64u + (unsigned)kg * 16u;
            a[i] = *(bf16x8*)(HBF + swz1k(off));
        }
        #pragma unroll
        for (int i = 0; i < 2; ++i)
            #pragma unroll
            for (int jj = 0; jj < 4; ++jj)
                acc[i][jj] = __builtin_amdgcn_mfma_f32_16x16x32_bf16(a[i], bcur[jj], acc[i][jj], 0, 0, 0);
        #pragma unroll
        for (int jj = 0; jj < 4; ++jj) bcur[jj] = bnext[jj];
    }

    // write T (bf16, swizzled rows) into TBF (C layout: row=kg*4+p, col=rl)
    #pragma unroll
    for (int i = 0; i < 2; ++i)
        #pragma unroll
        for (int jj = 0; jj < 4; ++jj)
            #pragma unroll
            for (int p = 0; p < 4; ++p) {
                unsigned row = (unsigned)(i * 16 + kg * 4 + p);
                unsigned col = (unsigned)(wv * 64 + jj * 16 + rl);
                *(unsigned short*)(TBF + swz1k(row * 1024u + col * 2u)) = f2bf(acc[i][jj][p]);
            }
    __syncthreads();

    // ---- Phase 3: waves 0-1: scores+softmax+w ; waves 2-5: residual pool
    if (wv < 2) {
        f32x4 sc = f32x4{0.f, 0.f, 0.f, 0.f};
        #pragma unroll
        for (int kc = 0; kc < 16; ++kc) {
            unsigned off = (unsigned)(wv * 16 + rl) * 1024u + (unsigned)kc * 64u + (unsigned)kg * 16u;
            bf16x8 aT = *(bf16x8*)(TBF + swz1k(off));
            bf16x8 bH = *(bf16x8*)(HBF + swz1k(off));   // H rows as B-operand == H^T
            sc = __builtin_amdgcn_mfma_f32_16x16x32_bf16(aT, bH, sc, 0, 0, 0);
        }
        const long long Bg = (long long)blockIdx.x * 2 + wv;
        const float* Fb = F + Bg * 16;
        float bias = logf(Fb[rl] + 1e-8f);              // bias for key column rl
        float alpha[4];
        #pragma unroll
        for (int p = 0; p < 4; ++p) {
            float s = sc[p] * 0.044194173824159216f + bias;  // 1/sqrt(512)
            float m = s;
            m = fmaxf(m, __shfl_xor(m, 8));
            m = fmaxf(m, __shfl_xor(m, 4));
            m = fmaxf(m, __shfl_xor(m, 2));
            m = fmaxf(m, __shfl_xor(m, 1));
            float e = expf(s - m);
            float sum = e;
            sum += __shfl_xor(sum, 8);
            sum += __shfl_xor(sum, 4);
            sum += __shfl_xor(sum, 2);
            sum += __shfl_xor(sum, 1);
            alpha[p] = e / sum;
        }
        float part = 0.f;
        #pragma unroll
        for (int p = 0; p < 4; ++p) part += Fb[kg * 4 + p] * alpha[p];
        part += __shfl_xor(part, 16);
        part += __shfl_xor(part, 32);
        if (ln < 16) wbuf[wv * 16 + ln] = part;
    } else if (wv < 6) {
        // residual F-pool: unit = (batch bb, d-half dh); lane covers 4 d-elems
        int u = wv - 2;
        int bb = u >> 1, dh = u & 1;
        const long long Bg = (long long)blockIdx.x * 2 + bb;
        const float* Fb = F + Bg * 16;
        int d0 = dh * 256 + ln * 4;
        float o[4];
        #pragma unroll
        for (int q = 0; q < 4; ++q) o[q] = 0.f;
        #pragma unroll
        for (int k = 0; k < 16; ++k) {
            unsigned off = (unsigned)(bb * 16 + k) * 1024u + (unsigned)d0 * 2u;
            ushort4 h = *(ushort4*)(HBF + swz1k(off));
            float fk = Fb[k];
            o[0] = fmaf(fk, bf2f(h.x), o[0]); o[1] = fmaf(fk, bf2f(h.y), o[1]);
            o[2] = fmaf(fk, bf2f(h.z), o[2]); o[3] = fmaf(fk, bf2f(h.w), o[3]);
        }
        float4 oa; oa.x = o[0]; oa.y = o[1]; oa.z = o[2]; oa.w = o[3];
        *(float4*)(out + Bg * 512 + d0) = oa;
    }
    __syncthreads();

    // ---- Phase 4: g (bf16). 8 waves = 2 batches x 4 d-quarters, from LDS.
    {
        int bb = wv >> 2, q4 = wv & 3;
        const long long Bg = (long long)blockIdx.x * 2 + bb;
        int d0 = q4 * 128 + ln * 2;
        float g0 = 0.f, g1 = 0.f;
        #pragma unroll
        for (int k = 0; k < 16; ++k) {
            unsigned off = (unsigned)(bb * 16 + k) * 1024u + (unsigned)d0 * 2u;
            ushort2 h = *(ushort2*)(HBF + swz1k(off));
            float wk = wbuf[bb * 16 + k];
            g0 = fmaf(wk, bf2f(h.x), g0); g1 = fmaf(wk, bf2f(h.y), g1);
        }
        ushort2 g2; g2.x = f2bf(g0); g2.y = f2bf(g1);
        *(ushort2*)(g_ws + Bg * 512 + d0) = g2;
    }
}

// ---------------- K3: out += g @ Wv^T   (8192x512 @ 512x512, bf16 MFMA)
__global__ __launch_bounds__(256) void out_gemm_kernel(
    const unsigned short* __restrict__ g_ws,
    const unsigned short* __restrict__ Wvb,
    float* __restrict__ out)
{
    extern __shared__ char smem[];  // 32 KB: 32 rows x 1024B, swizzled
    const int tid = threadIdx.x;
    const int wv = tid >> 6, ln = tid & 63;
    const int rl = ln & 15, kg = ln >> 4;
    const long long r0 = (long long)blockIdx.x * 32;
    {
        const uint4* src = (const uint4*)(g_ws + r0 * 512);
        #pragma unroll
        for (int q = 0; q < 8; ++q) {
            int idx = q * 256 + tid;
            *(uint4*)(smem + swz1k((unsigned)idx * 16u)) = src[idx];
        }
    }
    __syncthreads();
    f32x4 acc[2][8];
    #pragma unroll
    for (int i = 0; i < 2; ++i)
        #pragma unroll
        for (int jj = 0; jj < 8; ++jj)
            acc[i][jj] = f32x4{0.f, 0.f, 0.f, 0.f};
    for (int kc = 0; kc < 16; ++kc) {
        bf16x8 a[2];
        #pragma unroll
        for (int i = 0; i < 2; ++i) {
            unsigned off = (unsigned)(i * 16 + rl) * 1024u + (unsigned)kc * 64u + (unsigned)kg * 16u;
            a[i] = *(bf16x8*)(smem + swz1k(off));
        }
        bf16x8 bfr[8];
        #pragma unroll
        for (int jj = 0; jj < 8; ++jj) {
            int n = wv * 128 + jj * 16 + rl;
            bfr[jj] = *(const bf16x8*)(Wvb + n * 512 + kc * 32 + kg * 8);  // Wv[n][k] row-major
        }
        #pragma unroll
        for (int i = 0; i < 2; ++i)
            #pragma unroll
            for (int jj = 0; jj < 8; ++jj)
                acc[i][jj] = __builtin_amdgcn_mfma_f32_16x16x32_bf16(a[i], bfr[jj], acc[i][jj], 0, 0, 0);
    }
    #pragma unroll
    for (int i = 0; i < 2; ++i)
        #pragma unroll
        for (int jj = 0; jj < 8; ++jj)
            #pragma unroll
            for (int p = 0; p < 4; ++p) {
                int row = i * 16 + kg * 4 + p;
                int col = wv * 128 + jj * 16 + rl;
                out[(r0 + row) * 512 + col] += acc[i][jj][p];
            }
}

extern "C" void kernel_launch(void* const* d_in, const int* in_sizes, int n_in,
                              void* d_out, int out_size, void* d_ws, size_t ws_size,
                              hipStream_t stream)
{
    const float* H  = (const float*)d_in[0];
    const float* F  = (const float*)d_in[1];
    const float* Wq = (const float*)d_in[2];
    const float* Wk = (const float*)d_in[3];
    const float* Wv = (const float*)d_in[4];
    float* out = (float*)d_out;

    unsigned short* Pc  = (unsigned short*)d_ws;       // 16*512*32   = 262144 bf16
    unsigned short* Wvb = Pc + 262144;                 // 512*512     = 262144 bf16
    unsigned short* g   = Wvb + 262144;                // 8192*512    = 4194304 bf16
    (void)in_sizes; (void)n_in; (void)out_size; (void)ws_size;

    hipLaunchKernelGGL(prep_kernel, dim3(2048), dim3(256), 0, stream, Wq, Wk, Wv, Pc, Wvb);
    hipLaunchKernelGGL(attn_main_kernel, dim3(4096), dim3(512), 65664, stream, H, F, Pc, out, g);
    hipLaunchKernelGGL(out_gemm_kernel, dim3(256), dim3(256), 32768, stream, g, Wvb, out);
}